// Round 3
// baseline (184.899 us; speedup 1.0000x reference)
//
#include <hip/hip_runtime.h>
#include <hip/hip_bf16.h>

// SplineLoss: reference evaluates a not-a-knot cubic spline at INTEGER sample
// times t=0,10,...,8190 with knots at integers 0..8191 -> local parameter is
// exactly 0 for every sample, so the spline solve vanishes and the result is
// exactly:  mean_{b<1024, j<820} (true[b,10j] - pred[b,10j])^2
//
// Every 64B line of both 32MB inputs contains a multiple-of-10 element
// (stride 40B < 64B), so minimum HBM traffic = 64MB -> stream everything
// coalesced (float4) and predicate. Within a float4 group g (t=4g), samples
// land at .x when g%5==0 and .z when g%5==2 (period lcm(4,10)=20 elems).
//
// Single fused kernel: last-finishing block reduces the 2048 partials
// (saves the stage-2 dispatch serialization ~2-3us). Cross-XCD safety:
// partial stores are device-scope atomic RELEASE stores, ticket counter is
// device-scope ACQ_REL, winner reads partials with device-scope atomic loads
// (per-XCD L2s are not coherent; plain ld/st could see stale 0xAA poison).

#define B_ROWS   1024
#define N_COLS   8192
#define N_SAMP   820
#define BLOCK    256
#define SPLIT    2                         // blocks per row
#define GRID     (B_ROWS * SPLIT)          // 2048 partials
#define GROUPS_PER_ROW   (N_COLS / 4)      // 2048 float4 groups
#define GROUPS_PER_BLOCK (GROUPS_PER_ROW / SPLIT)  // 1024

__global__ __launch_bounds__(BLOCK)
void spline_loss_fused(const float* __restrict__ tf,
                       const float* __restrict__ pf,
                       float* __restrict__ partial,
                       unsigned int* __restrict__ counter,
                       float* __restrict__ out) {
    const int b    = blockIdx.x >> 1;          // row
    const int half = blockIdx.x & 1;           // which half of the row
    const float4* t4 = (const float4*)(tf + (size_t)b * N_COLS);
    const float4* p4 = (const float4*)(pf + (size_t)b * N_COLS);

    float acc = 0.0f;
    #pragma unroll
    for (int k = 0; k < GROUPS_PER_BLOCK / BLOCK; ++k) {   // 4 iters
        const int g = half * GROUPS_PER_BLOCK + k * BLOCK + threadIdx.x;
        float4 a = t4[g];
        float4 c = p4[g];
        const int r = g % 5;                   // magic-mul, cheap
        const float d0 = a.x - c.x;
        const float d2 = a.z - c.z;
        acc += (r == 0) ? d0 * d0 : 0.0f;
        acc += (r == 2) ? d2 * d2 : 0.0f;
    }

    // wave-64 shuffle reduction, then cross-wave via LDS
    #pragma unroll
    for (int off = 32; off > 0; off >>= 1)
        acc += __shfl_down(acc, off, 64);

    __shared__ float wsum[BLOCK / 64];
    __shared__ int   last;
    const int lane = threadIdx.x & 63;
    const int wid  = threadIdx.x >> 6;
    if (lane == 0) wsum[wid] = acc;
    __syncthreads();

    if (threadIdx.x == 0) {
        float s = 0.0f;
        #pragma unroll
        for (int w = 0; w < BLOCK / 64; ++w) s += wsum[w];
        // device-scope release store: visible to any XCD that acquires later
        __hip_atomic_store(&partial[blockIdx.x], s,
                           __ATOMIC_RELEASE, __HIP_MEMORY_SCOPE_AGENT);
        const unsigned int ticket =
            __hip_atomic_fetch_add(counter, 1u,
                                   __ATOMIC_ACQ_REL, __HIP_MEMORY_SCOPE_AGENT);
        last = (ticket == GRID - 1);           // winner = last block to finish
    }
    __syncthreads();

    if (last) {
        // final reduction by the winning block (all prior releases are
        // ordered before our acquire on the counter)
        float a2 = 0.0f;
        #pragma unroll
        for (int k = 0; k < GRID / BLOCK; ++k)  // 8 coherent loads/thread
            a2 += __hip_atomic_load(&partial[k * BLOCK + threadIdx.x],
                                    __ATOMIC_RELAXED, __HIP_MEMORY_SCOPE_AGENT);
        #pragma unroll
        for (int off = 32; off > 0; off >>= 1)
            a2 += __shfl_down(a2, off, 64);
        __syncthreads();                        // reuse wsum safely
        if (lane == 0) wsum[wid] = a2;
        __syncthreads();
        if (threadIdx.x == 0) {
            float s = 0.0f;
            #pragma unroll
            for (int w = 0; w < BLOCK / 64; ++w) s += wsum[w];
            out[0] = s * (1.0f / (float)(B_ROWS * N_SAMP));
        }
    }
}

extern "C" void kernel_launch(void* const* d_in, const int* in_sizes, int n_in,
                              void* d_out, int out_size, void* d_ws, size_t ws_size,
                              hipStream_t stream) {
    const float* tf = (const float*)d_in[0];   // true_frames  (1024, 8192) f32
    const float* pf = (const float*)d_in[1];   // predicted_frames
    float* out     = (float*)d_out;            // scalar f32
    float* partial = (float*)d_ws;             // 2048 floats
    unsigned int* counter = (unsigned int*)((char*)d_ws + GRID * sizeof(float));

    // counter is poisoned 0xAA by the harness each iteration -> zero it.
    // 4-byte memset node is cheaper than a second kernel dispatch.
    hipMemsetAsync(counter, 0, sizeof(unsigned int), stream);

    spline_loss_fused<<<GRID, BLOCK, 0, stream>>>(tf, pf, partial, counter, out);
}

// Round 4
// 91.335 us; speedup vs baseline: 2.0244x; 2.0244x over previous
//
#include <hip/hip_runtime.h>
#include <hip/hip_bf16.h>

// SplineLoss: reference evaluates a not-a-knot cubic spline at INTEGER sample
// times t=0,10,...,8190 with knots at integers 0..8191 -> local parameter is
// exactly 0 for every sample, so the spline solve vanishes and the result is
// exactly:  mean_{b<1024, j<820} (true[b,10j] - pred[b,10j])^2
//
// Stride 40B < 64B line -> every line of both 32MB inputs is needed; minimum
// traffic 64MB, roofline ~10.2us at 6.3TB/s. Within float4 group g (t=4g),
// samples land at .x when g%5==0 and .z when g%5==2.
//
// R3 lesson 1: per-block agent-scope acq_rel fences are catastrophic
// (~+90us for 2048 blocks) -> two-dispatch reduction, no device fences.
// R3 lesson 2: the R1/R2 loop compiled to VGPR=12 -> only ~2 loads in
// flight -> latency-bound at ~450GB/s effective (213GB/s HBM-side).
// Fix: load all 8 float4s into named registers BEFORE any use -> 8
// independent global_load_dwordx4 in flight (8KB/wave MLP).

#define B_ROWS   1024
#define N_COLS   8192
#define N_SAMP   820
#define BLOCK    256
#define SPLIT    2                         // blocks per row
#define GRID     (B_ROWS * SPLIT)          // 2048 partials
#define GROUPS_PER_ROW   (N_COLS / 4)      // 2048 float4 groups
#define GROUPS_PER_BLOCK (GROUPS_PER_ROW / SPLIT)  // 1024

__global__ __launch_bounds__(BLOCK)
void spline_partial_kernel(const float* __restrict__ tf,
                           const float* __restrict__ pf,
                           float* __restrict__ partial) {
    const int b    = blockIdx.x >> 1;          // row
    const int half = blockIdx.x & 1;           // which half of the row
    const float4* t4 = (const float4*)(tf + (size_t)b * N_COLS);
    const float4* p4 = (const float4*)(pf + (size_t)b * N_COLS);

    const int g0 = half * GROUPS_PER_BLOCK + threadIdx.x;

    // ---- all 8 loads issued before any use: 8 x global_load_dwordx4 ----
    const float4 a0 = t4[g0];
    const float4 a1 = t4[g0 + 256];
    const float4 a2 = t4[g0 + 512];
    const float4 a3 = t4[g0 + 768];
    const float4 c0 = p4[g0];
    const float4 c1 = p4[g0 + 256];
    const float4 c2 = p4[g0 + 512];
    const float4 c3 = p4[g0 + 768];

    // ---- predicated squared-diff accumulate (VALU is ~1% busy, cheap) ----
    float acc = 0.0f;
    {
        const int r = g0 % 5;                       // 256%5==1: r advances +1/step
        float d;
        d = a0.x - c0.x; acc += (r == 0) ? d * d : 0.0f;
        d = a0.z - c0.z; acc += (r == 2) ? d * d : 0.0f;
        const int r1 = (r + 1 >= 5) ? r - 4 : r + 1;
        d = a1.x - c1.x; acc += (r1 == 0) ? d * d : 0.0f;
        d = a1.z - c1.z; acc += (r1 == 2) ? d * d : 0.0f;
        const int r2 = (r1 + 1 >= 5) ? r1 - 4 : r1 + 1;
        d = a2.x - c2.x; acc += (r2 == 0) ? d * d : 0.0f;
        d = a2.z - c2.z; acc += (r2 == 2) ? d * d : 0.0f;
        const int r3 = (r2 + 1 >= 5) ? r2 - 4 : r2 + 1;
        d = a3.x - c3.x; acc += (r3 == 0) ? d * d : 0.0f;
        d = a3.z - c3.z; acc += (r3 == 2) ? d * d : 0.0f;
    }

    // wave-64 shuffle reduction
    #pragma unroll
    for (int off = 32; off > 0; off >>= 1)
        acc += __shfl_down(acc, off, 64);

    __shared__ float wsum[BLOCK / 64];
    const int lane = threadIdx.x & 63;
    const int wid  = threadIdx.x >> 6;
    if (lane == 0) wsum[wid] = acc;
    __syncthreads();

    if (threadIdx.x == 0) {
        float s = 0.0f;
        #pragma unroll
        for (int w = 0; w < BLOCK / 64; ++w) s += wsum[w];
        partial[blockIdx.x] = s;               // plain store; next dispatch sees it
    }
}

__global__ __launch_bounds__(BLOCK)
void spline_final_kernel(const float* __restrict__ partial,
                         float* __restrict__ out) {
    float acc = 0.0f;
    #pragma unroll
    for (int k = 0; k < GRID / BLOCK; ++k)     // 8 coalesced loads
        acc += partial[k * BLOCK + threadIdx.x];

    #pragma unroll
    for (int off = 32; off > 0; off >>= 1)
        acc += __shfl_down(acc, off, 64);

    __shared__ float wsum[BLOCK / 64];
    const int lane = threadIdx.x & 63;
    const int wid  = threadIdx.x >> 6;
    if (lane == 0) wsum[wid] = acc;
    __syncthreads();

    if (threadIdx.x == 0) {
        float s = 0.0f;
        #pragma unroll
        for (int w = 0; w < BLOCK / 64; ++w) s += wsum[w];
        out[0] = s * (1.0f / (float)(B_ROWS * N_SAMP));  // overwrite, no memset
    }
}

extern "C" void kernel_launch(void* const* d_in, const int* in_sizes, int n_in,
                              void* d_out, int out_size, void* d_ws, size_t ws_size,
                              hipStream_t stream) {
    const float* tf = (const float*)d_in[0];   // true_frames  (1024, 8192) f32
    const float* pf = (const float*)d_in[1];   // predicted_frames
    float* out     = (float*)d_out;            // scalar f32
    float* partial = (float*)d_ws;             // 2048 floats of scratch

    spline_partial_kernel<<<GRID, BLOCK, 0, stream>>>(tf, pf, partial);
    spline_final_kernel<<<1, BLOCK, 0, stream>>>(partial, out);
}